// Round 2
// baseline (1836.833 us; speedup 1.0000x reference)
//
#include <hip/hip_runtime.h>

#define TSTEPS 1024

// 4 FMAs accumulating a float4 LDS broadcast against a register weight array.
// NOTE: parameter names end in '_' so they can't capture the .x/.y/.z/.w fields.
#define ACC4(acc_, wt_, q_, hv_)                    \
    acc_ = fmaf((wt_)[4*(q_)+0], (hv_).x, acc_);    \
    acc_ = fmaf((wt_)[4*(q_)+1], (hv_).y, acc_);    \
    acc_ = fmaf((wt_)[4*(q_)+2], (hv_).z, acc_);    \
    acc_ = fmaf((wt_)[4*(q_)+3], (hv_).w, acc_);

__device__ __forceinline__ float fast_rcp(float x) { return __builtin_amdgcn_rcpf(x); }
__device__ __forceinline__ float fast_sigmoid(float x) {
    // sigmoid(x) = 1/(1+exp(-x)); saturates correctly at +/-inf
    return fast_rcp(1.0f + __expf(-x));
}
__device__ __forceinline__ float fast_tanh(float x) {
    // tanh(x) = 1 - 2/(exp(2x)+1); saturates correctly at +/-inf
    float e = __expf(2.0f * x);
    return 1.0f - 2.0f * fast_rcp(e + 1.0f);
}

// One wave (64 lanes) per batch element. Lane j owns GRU1 gate rows
// {j, 64+j, 128+j} (weights in VGPRs) and updates h1[j] locally.
// Lanes 0..47 own GRU2 rows {j, j+48} of the 96 gate rows.
// h1/h2 broadcast through LDS; single-wave workgroup so __syncthreads is cheap.
__global__ __launch_bounds__(64, 1)
void gru2_encoder(const float* __restrict__ x,
                  const float* __restrict__ W_ih1,
                  const float* __restrict__ W_hh1,
                  const float* __restrict__ b_ih1,
                  const float* __restrict__ b_hh1,
                  const float* __restrict__ W_ih2,
                  const float* __restrict__ W_hh2,
                  const float* __restrict__ b_ih2,
                  const float* __restrict__ b_hh2,
                  float* __restrict__ out)
{
    const int b = blockIdx.x;
    const int j = threadIdx.x;  // 0..63

    __shared__ __align__(16) float s_h1[64];
    __shared__ __align__(16) float s_h2[32];
    __shared__ __align__(16) float s_g2[128];

    // ---- GRU1 weights: W_hh1 is [192][64]; lane j holds rows j (r), 64+j (z), 128+j (n)
    float w_r[64], w_z[64], w_n[64];
    {
        const float4* pr = (const float4*)(W_hh1 + (size_t)(j) * 64);
        const float4* pz = (const float4*)(W_hh1 + (size_t)(64 + j) * 64);
        const float4* pn = (const float4*)(W_hh1 + (size_t)(128 + j) * 64);
        #pragma unroll
        for (int q = 0; q < 16; ++q) {
            float4 v;
            v = pr[q]; w_r[4*q]=v.x; w_r[4*q+1]=v.y; w_r[4*q+2]=v.z; w_r[4*q+3]=v.w;
            v = pz[q]; w_z[4*q]=v.x; w_z[4*q+1]=v.y; w_z[4*q+2]=v.z; w_z[4*q+3]=v.w;
            v = pn[q]; w_n[4*q]=v.x; w_n[4*q+1]=v.y; w_n[4*q+2]=v.z; w_n[4*q+3]=v.w;
        }
    }
    const float wx_r = W_ih1[j];
    const float wx_z = W_ih1[64 + j];
    const float wx_n = W_ih1[128 + j];
    const float bias_r  = b_ih1[j]      + b_hh1[j];
    const float bias_z  = b_ih1[64 + j] + b_hh1[64 + j];
    const float bias_xn = b_ih1[128 + j];
    const float bias_hn = b_hh1[128 + j];

    // ---- GRU2 weights: W_ih2 [96][64], W_hh2 [96][32]; lanes 0..47 own rows rA=j, rB=j+48
    const bool act = (j < 48);
    const int rA = act ? j : 0;        // clamp so idle lanes load in-bounds garbage
    const int rB = act ? j + 48 : 0;
    float wA_i[64], wB_i[64], wA_h[32], wB_h[32];
    {
        const float4* pa = (const float4*)(W_ih2 + (size_t)rA * 64);
        const float4* pb = (const float4*)(W_ih2 + (size_t)rB * 64);
        #pragma unroll
        for (int q = 0; q < 16; ++q) {
            float4 v;
            v = pa[q]; wA_i[4*q]=v.x; wA_i[4*q+1]=v.y; wA_i[4*q+2]=v.z; wA_i[4*q+3]=v.w;
            v = pb[q]; wB_i[4*q]=v.x; wB_i[4*q+1]=v.y; wB_i[4*q+2]=v.z; wB_i[4*q+3]=v.w;
        }
        const float4* qa = (const float4*)(W_hh2 + (size_t)rA * 32);
        const float4* qb = (const float4*)(W_hh2 + (size_t)rB * 32);
        #pragma unroll
        for (int q = 0; q < 8; ++q) {
            float4 v;
            v = qa[q]; wA_h[4*q]=v.x; wA_h[4*q+1]=v.y; wA_h[4*q+2]=v.z; wA_h[4*q+3]=v.w;
            v = qb[q]; wB_h[4*q]=v.x; wB_h[4*q+1]=v.y; wB_h[4*q+2]=v.z; wB_h[4*q+3]=v.w;
        }
    }
    const float bAx = b_ih2[rA], bAh = b_hh2[rA];
    const float bBx = b_ih2[rB], bBh = b_hh2[rB];

    // ---- init state
    float h1  = 0.0f;   // h1[j]
    float h2u = 0.0f;   // h2[j] for j<32
    s_h1[j] = 0.0f;
    if (j < 32) s_h2[j] = 0.0f;
    __syncthreads();

    const float* xrow = x + (size_t)b * TSTEPS;
    float xv = xrow[0];

    for (int t = 0; t < TSTEPS; ++t) {
        float xv_next = (t + 1 < TSTEPS) ? xrow[t + 1] : 0.0f;  // prefetch

        // Phase D: gh2 over OLD h2  (must precede h2 write)
        float accAh = bAh, accBh = bBh;
        #pragma unroll
        for (int q = 0; q < 8; ++q) {
            float4 hv = ((const float4*)s_h2)[q];
            ACC4(accAh, wA_h, q, hv)
            ACC4(accBh, wB_h, q, hv)
        }

        // Phase A: gh1 over OLD h1
        float acc_r  = fmaf(wx_r, xv, bias_r);
        float acc_z  = fmaf(wx_z, xv, bias_z);
        float acc_hn = bias_hn;
        #pragma unroll
        for (int q = 0; q < 16; ++q) {
            float4 hv = ((const float4*)s_h1)[q];
            ACC4(acc_r,  w_r, q, hv)
            ACC4(acc_z,  w_z, q, hv)
            ACC4(acc_hn, w_n, q, hv)
        }

        // Phase B: GRU1 gate math + h1 update (all local to lane j)
        float r = fast_sigmoid(acc_r);
        float z = fast_sigmoid(acc_z);
        float n = fast_tanh(fmaf(wx_n, xv, bias_xn) + r * acc_hn);
        h1 = n + z * (h1 - n);
        __syncthreads();              // all lanes done reading old s_h1
        s_h1[j] = h1;
        __syncthreads();

        // Phase C: gx2 over NEW h1
        float accAx = bAx, accBx = bBx;
        #pragma unroll
        for (int q = 0; q < 16; ++q) {
            float4 hv = ((const float4*)s_h1)[q];
            ACC4(accAx, wA_i, q, hv)
            ACC4(accBx, wB_i, q, hv)
        }

        // Exchange GRU2 pre-activations.
        // Row meaning: 0..31 r2 | 32..63 z2 | 64..95 n2 (n2 keeps gx/gh parts split)
        if (act) {
            s_g2[rA] = accAx + accAh;            // rA in 0..47: r2 or z2 -> merged
            if (rB < 64) {
                s_g2[rB] = accBx + accBh;        // z2
            } else {
                s_g2[rB]      = accBx;           // n2: gx part (incl b_ih2)
                s_g2[rB + 32] = accBh;           // n2: gh part (incl b_hh2)
            }
        }
        __syncthreads();

        // Phase E: h2 update on lanes 0..31
        if (j < 32) {
            float r2 = fast_sigmoid(s_g2[j]);
            float z2 = fast_sigmoid(s_g2[32 + j]);
            float n2 = fast_tanh(s_g2[64 + j] + r2 * s_g2[96 + j]);
            h2u = n2 + z2 * (h2u - n2);
        }
        __syncthreads();              // g2 reads done; old-h2 reads long done
        if (j < 32) s_h2[j] = h2u;
        __syncthreads();              // next step reads s_h2

        xv = xv_next;
    }

    if (j < 32) out[(size_t)b * 32 + j] = h2u;
}

extern "C" void kernel_launch(void* const* d_in, const int* in_sizes, int n_in,
                              void* d_out, int out_size, void* d_ws, size_t ws_size,
                              hipStream_t stream) {
    const float* x     = (const float*)d_in[0];
    const float* W_ih1 = (const float*)d_in[1];
    const float* W_hh1 = (const float*)d_in[2];
    const float* b_ih1 = (const float*)d_in[3];
    const float* b_hh1 = (const float*)d_in[4];
    const float* W_ih2 = (const float*)d_in[5];
    const float* W_hh2 = (const float*)d_in[6];
    const float* b_ih2 = (const float*)d_in[7];
    const float* b_hh2 = (const float*)d_in[8];
    float* out = (float*)d_out;

    gru2_encoder<<<dim3(1024), dim3(64), 0, stream>>>(
        x, W_ih1, W_hh1, b_ih1, b_hh1, W_ih2, W_hh2, b_ih2, b_hh2, out);
}

// Round 3
// 834.293 us; speedup vs baseline: 2.2017x; 2.2017x over previous
//
#include <hip/hip_runtime.h>

#define TSTEPS 1024

// 4 FMAs accumulating a float4 LDS broadcast against a register weight array.
#define ACC4(acc_, wt_, q_, hv_)                    \
    acc_ = fmaf((wt_)[4*(q_)+0], (hv_).x, acc_);    \
    acc_ = fmaf((wt_)[4*(q_)+1], (hv_).y, acc_);    \
    acc_ = fmaf((wt_)[4*(q_)+2], (hv_).z, acc_);    \
    acc_ = fmaf((wt_)[4*(q_)+3], (hv_).w, acc_);

__device__ __forceinline__ float fast_rcp(float x) { return __builtin_amdgcn_rcpf(x); }
__device__ __forceinline__ float fast_sigmoid(float x) {
    return fast_rcp(1.0f + __expf(-x));
}
__device__ __forceinline__ float fast_tanh(float x) {
    float e = __expf(2.0f * x);
    return 1.0f - 2.0f * fast_rcp(e + 1.0f);
}

// Two waves per block (one block per batch element), layer-pipelined:
//   wave 0: GRU1. lane j owns W_hh1 rows {j, 64+j, 128+j} (192 regs), updates h1[j].
//           Writes h1(t) to double-buffer s_h1[t&1].
//   wave 1: GRU2, one step behind. lane (u=lane&31, half=lane>>5) owns a K-split
//           of gate rows {u, 32+u, 64+u}: W_ih2 cols [half*32,+32), W_hh2 cols
//           [half*16,+16) (144 regs). Cross-half reduce via shfl_xor(32).
// One workgroup barrier per tick; wave1's internal h2 broadcast is intra-wave
// (in-order LDS + lgkmcnt wait; the end-of-tick barrier orders it across ticks).
__global__ __launch_bounds__(128, 2)
void gru2_encoder(const float* __restrict__ x,
                  const float* __restrict__ W_ih1,
                  const float* __restrict__ W_hh1,
                  const float* __restrict__ b_ih1,
                  const float* __restrict__ b_hh1,
                  const float* __restrict__ W_ih2,
                  const float* __restrict__ W_hh2,
                  const float* __restrict__ b_ih2,
                  const float* __restrict__ b_hh2,
                  float* __restrict__ out)
{
    const int b    = blockIdx.x;
    const int lane = threadIdx.x & 63;
    const int wid  = threadIdx.x >> 6;

    __shared__ __align__(16) float s_h1[2][64];  // h1 double buffer (producer->consumer)
    __shared__ __align__(16) float s_h2[32];     // wave1-internal h2 broadcast

    if (wid == 0) {
        // ================= WAVE 0 : GRU1 producer =================
        const int j = lane;
        float w_r[64], w_z[64], w_n[64];
        {
            const float4* pr = (const float4*)(W_hh1 + (size_t)(j) * 64);
            const float4* pz = (const float4*)(W_hh1 + (size_t)(64 + j) * 64);
            const float4* pn = (const float4*)(W_hh1 + (size_t)(128 + j) * 64);
            #pragma unroll
            for (int q = 0; q < 16; ++q) {
                float4 v;
                v = pr[q]; w_r[4*q]=v.x; w_r[4*q+1]=v.y; w_r[4*q+2]=v.z; w_r[4*q+3]=v.w;
                v = pz[q]; w_z[4*q]=v.x; w_z[4*q+1]=v.y; w_z[4*q+2]=v.z; w_z[4*q+3]=v.w;
                v = pn[q]; w_n[4*q]=v.x; w_n[4*q+1]=v.y; w_n[4*q+2]=v.z; w_n[4*q+3]=v.w;
            }
        }
        const float wx_r = W_ih1[j];
        const float wx_z = W_ih1[64 + j];
        const float wx_n = W_ih1[128 + j];
        const float bias_r  = b_ih1[j]      + b_hh1[j];
        const float bias_z  = b_ih1[64 + j] + b_hh1[64 + j];
        const float bias_xn = b_ih1[128 + j];
        const float bias_hn = b_hh1[128 + j];

        float h1 = 0.0f;
        s_h1[0][j] = 0.0f;
        s_h1[1][j] = 0.0f;
        __syncthreads();   // matches wave1's init barrier

        const float* xrow = x + (size_t)b * TSTEPS;
        float xs = 0.0f;   // 64 timesteps of x, lane-distributed

        for (int t = 0; t <= TSTEPS; ++t) {
            if (t < TSTEPS) {
                if ((t & 63) == 0) xs = xrow[t + j];   // one coalesced load / 64 ticks
                const float xv = __shfl(xs, t & 63);

                const float4* ph = (const float4*)s_h1[(t + 1) & 1];  // h1(t-1)
                float acc_r  = fmaf(wx_r, xv, bias_r);
                float acc_z  = fmaf(wx_z, xv, bias_z);
                float acc_hn = bias_hn;
                #pragma unroll
                for (int q = 0; q < 16; ++q) {
                    float4 hv = ph[q];
                    ACC4(acc_r,  w_r, q, hv)
                    ACC4(acc_z,  w_z, q, hv)
                    ACC4(acc_hn, w_n, q, hv)
                }
                float r = fast_sigmoid(acc_r);
                float z = fast_sigmoid(acc_z);
                float n = fast_tanh(fmaf(wx_n, xv, bias_xn) + r * acc_hn);
                h1 = n + z * (h1 - n);
                s_h1[t & 1][j] = h1;
            }
            __syncthreads();
        }
    } else {
        // ================= WAVE 1 : GRU2 consumer (one step behind) =================
        const int u    = lane & 31;   // hidden unit
        const int half = lane >> 5;   // K-split half
        float wi_r[32], wi_z[32], wi_n[32];   // W_ih2 row slices (cols half*32..+32)
        float wh_r[16], wh_z[16], wh_n[16];   // W_hh2 row slices (cols half*16..+16)
        {
            const float4* pr = (const float4*)(W_ih2 + (size_t)(u)      * 64 + half * 32);
            const float4* pz = (const float4*)(W_ih2 + (size_t)(32 + u) * 64 + half * 32);
            const float4* pn = (const float4*)(W_ih2 + (size_t)(64 + u) * 64 + half * 32);
            #pragma unroll
            for (int q = 0; q < 8; ++q) {
                float4 v;
                v = pr[q]; wi_r[4*q]=v.x; wi_r[4*q+1]=v.y; wi_r[4*q+2]=v.z; wi_r[4*q+3]=v.w;
                v = pz[q]; wi_z[4*q]=v.x; wi_z[4*q+1]=v.y; wi_z[4*q+2]=v.z; wi_z[4*q+3]=v.w;
                v = pn[q]; wi_n[4*q]=v.x; wi_n[4*q+1]=v.y; wi_n[4*q+2]=v.z; wi_n[4*q+3]=v.w;
            }
            const float4* qr = (const float4*)(W_hh2 + (size_t)(u)      * 32 + half * 16);
            const float4* qz = (const float4*)(W_hh2 + (size_t)(32 + u) * 32 + half * 16);
            const float4* qn = (const float4*)(W_hh2 + (size_t)(64 + u) * 32 + half * 16);
            #pragma unroll
            for (int q = 0; q < 4; ++q) {
                float4 v;
                v = qr[q]; wh_r[4*q]=v.x; wh_r[4*q+1]=v.y; wh_r[4*q+2]=v.z; wh_r[4*q+3]=v.w;
                v = qz[q]; wh_z[4*q]=v.x; wh_z[4*q+1]=v.y; wh_z[4*q+2]=v.z; wh_z[4*q+3]=v.w;
                v = qn[q]; wh_n[4*q]=v.x; wh_n[4*q+1]=v.y; wh_n[4*q+2]=v.z; wh_n[4*q+3]=v.w;
            }
        }
        const float bR  = b_ih2[u]      + b_hh2[u];
        const float bZ  = b_ih2[32 + u] + b_hh2[32 + u];
        const float bNx = b_ih2[64 + u];
        const float bNh = b_hh2[64 + u];

        float h2 = 0.0f;              // h2[u], replicated in both halves
        if (lane < 32) s_h2[lane] = 0.0f;
        __syncthreads();   // matches wave0's init barrier

        for (int t = 0; t <= TSTEPS; ++t) {
            if (t >= 1) {
                const float4* ph1 = (const float4*)(&s_h1[(t - 1) & 1][half * 32]); // h1(t-1)
                float accR = 0.0f, accZ = 0.0f, accNx = 0.0f, accNh = 0.0f;
                #pragma unroll
                for (int q = 0; q < 8; ++q) {
                    float4 hv = ph1[q];
                    ACC4(accR,  wi_r, q, hv)
                    ACC4(accZ,  wi_z, q, hv)
                    ACC4(accNx, wi_n, q, hv)
                }
                const float4* ph2 = (const float4*)(&s_h2[half * 16]);              // h2(t-2)
                #pragma unroll
                for (int q = 0; q < 4; ++q) {
                    float4 hv = ph2[q];
                    ACC4(accR,  wh_r, q, hv)
                    ACC4(accZ,  wh_z, q, hv)
                    ACC4(accNh, wh_n, q, hv)
                }
                // cross-half reduction (full sums land on both halves)
                accR  += __shfl_xor(accR,  32);
                accZ  += __shfl_xor(accZ,  32);
                accNx += __shfl_xor(accNx, 32);
                accNh += __shfl_xor(accNh, 32);

                float r2 = fast_sigmoid(accR + bR);
                float z2 = fast_sigmoid(accZ + bZ);
                float n2 = fast_tanh(accNx + bNx + r2 * (accNh + bNh));
                h2 = n2 + z2 * (h2 - n2);

                // drain this tick's s_h2 reads before overwriting (same-wave WAR);
                // cross-tick visibility is ordered by the workgroup barrier below.
                asm volatile("s_waitcnt lgkmcnt(0)" ::: "memory");
                if (lane < 32) s_h2[lane] = h2;
            }
            __syncthreads();
        }

        if (lane < 32) out[(size_t)b * 32 + lane] = h2;
    }
}

extern "C" void kernel_launch(void* const* d_in, const int* in_sizes, int n_in,
                              void* d_out, int out_size, void* d_ws, size_t ws_size,
                              hipStream_t stream) {
    const float* x     = (const float*)d_in[0];
    const float* W_ih1 = (const float*)d_in[1];
    const float* W_hh1 = (const float*)d_in[2];
    const float* b_ih1 = (const float*)d_in[3];
    const float* b_hh1 = (const float*)d_in[4];
    const float* W_ih2 = (const float*)d_in[5];
    const float* W_hh2 = (const float*)d_in[6];
    const float* b_ih2 = (const float*)d_in[7];
    const float* b_hh2 = (const float*)d_in[8];
    float* out = (float*)d_out;

    gru2_encoder<<<dim3(1024), dim3(128), 0, stream>>>(
        x, W_ih1, W_hh1, b_ih1, b_hh1, W_ih2, W_hh2, b_ih2, b_hh2, out);
}